// Round 7
// baseline (231.327 us; speedup 1.0000x reference)
//
#include <hip/hip_runtime.h>

typedef unsigned short u16;
typedef short short8 __attribute__((ext_vector_type(8)));
typedef float floatx4 __attribute__((ext_vector_type(4)));
typedef u16 u16x4 __attribute__((ext_vector_type(4)));
typedef u16 u16x8 __attribute__((ext_vector_type(8)));

#define DEVI __device__ __forceinline__

DEVI u16 f2bf(float x) {
    union { float f; unsigned u; } c; c.f = x;
    unsigned u = c.u;
    u += 0x7fffu + ((u >> 16) & 1u);   // RNE
    return (u16)(u >> 16);
}
DEVI float bf2f(u16 h) {
    union { unsigned u; float f; } c; c.u = ((unsigned)h) << 16;
    return c.f;
}

DEVI void gload_lds16(const void* g, void* l) {
    auto gp = (const __attribute__((address_space(1))) unsigned*)(unsigned long long)g;
    auto lp = (__attribute__((address_space(3))) unsigned*)(unsigned)(unsigned long long)l;
    __builtin_amdgcn_global_load_lds(gp, lp, 16, 0, 0);
}

// ---------------- fused GroupNorm: single global read, stats + apply in regs ----------------
__global__ __launch_bounds__(256) void gn_fused_kernel(const float* __restrict__ x,
                                                       const float* __restrict__ w,
                                                       const float* __restrict__ bb,
                                                       u16* __restrict__ h) {
    const int bg = blockIdx.x;           // b*32+g
    const int b = bg >> 5, g = bg & 31;
    const float* xg = x + (long long)bg * 16384;
    const int n0 = threadIdx.x * 4;

    float4 xv[16];
    float s = 0.f, s2 = 0.f;
    #pragma unroll
    for (int cc = 0; cc < 16; cc++) {
        xv[cc] = *(const float4*)&xg[cc * 1024 + n0];
        s  += xv[cc].x + xv[cc].y + xv[cc].z + xv[cc].w;
        s2 += xv[cc].x*xv[cc].x + xv[cc].y*xv[cc].y + xv[cc].z*xv[cc].z + xv[cc].w*xv[cc].w;
    }
    #pragma unroll
    for (int m = 1; m < 64; m <<= 1) { s += __shfl_xor(s, m, 64); s2 += __shfl_xor(s2, m, 64); }
    __shared__ float rs[4], rq[4];
    if ((threadIdx.x & 63) == 0) { rs[threadIdx.x >> 6] = s; rq[threadIdx.x >> 6] = s2; }
    __syncthreads();
    float mean = (rs[0] + rs[1] + rs[2] + rs[3]) * (1.f / 16384.f);
    float var  = (rq[0] + rq[1] + rq[2] + rq[3]) * (1.f / 16384.f) - mean * mean;
    float rstd = rsqrtf(var + 1e-5f);

    u16x8 o[4][2];
    #pragma unroll
    for (int cc = 0; cc < 16; cc++) {
        int c = g * 16 + cc;
        float sc = w[c] * rstd;
        float sh = bb[c] - mean * sc;
        o[0][cc >> 3][cc & 7] = f2bf(xv[cc].x * sc + sh);
        o[1][cc >> 3][cc & 7] = f2bf(xv[cc].y * sc + sh);
        o[2][cc >> 3][cc & 7] = f2bf(xv[cc].z * sc + sh);
        o[3][cc >> 3][cc & 7] = f2bf(xv[cc].w * sc + sh);
    }
    u16* hb = h + ((long long)b * 1024 + n0) * 512 + g * 16;
    #pragma unroll
    for (int k = 0; k < 4; k++) {
        *(u16x8*)&hb[(long long)k * 512]     = o[k][0];
        *(u16x8*)&hb[(long long)k * 512 + 8] = o[k][1];
    }
}

// ---------------- weight prep: convert qk rows + wo, transpose v-weight block ----------------
// blocks 0..767: bulk fp32->bf16 (wqk: rows 0..1023 of qkv_w; wo: full out_w)
// blocks 768..1023: 32x32 LDS transpose tiles of qkv_w rows 1024..1535 -> wvT[ci][cv] bf16
__global__ __launch_bounds__(256) void wprep_kernel(const float* __restrict__ qkv_w,
                                                    u16* __restrict__ wqk,
                                                    const float* __restrict__ out_w,
                                                    u16* __restrict__ wo,
                                                    u16* __restrict__ wvT) {
    const int blk = blockIdx.x;
    if (blk < 768) {
        int i = blk * 256 + threadIdx.x;   // float4 slot
        const float* src; u16* dst; int j;
        if (i < 131072) { src = qkv_w; dst = wqk; j = i; }
        else            { src = out_w; dst = wo;  j = i - 131072; }
        float4 v = *(const float4*)&src[j * 4];
        u16x4 p; p[0] = f2bf(v.x); p[1] = f2bf(v.y); p[2] = f2bf(v.z); p[3] = f2bf(v.w);
        *(u16x4*)&dst[j * 4] = p;
    } else {
        const int tt = blk - 768;          // 256 tiles: 16x16 of 32x32
        const int tr = tt >> 4, tc = tt & 15;   // tr: ci tile, tc: cv tile
        const int tx = threadIdx.x & 31, ty = threadIdx.x >> 5;  // 32 x 8
        __shared__ float tl[32][33];
        #pragma unroll
        for (int p = 0; p < 4; p++) {
            int cvl = ty + p * 8;
            tl[cvl][tx] = qkv_w[(long long)(1024 + tc * 32 + cvl) * 512 + tr * 32 + tx];
        }
        __syncthreads();
        #pragma unroll
        for (int p = 0; p < 4; p++) {
            int cil = ty + p * 8;
            wvT[(long long)(tr * 32 + cil) * 512 + tc * 32 + tx] = f2bf(tl[tx][cil]);
        }
    }
}

// ---------------- biasout[c] = out_b[c] + sum_cv out_w[c][cv]*qkv_b[1024+cv] ----------------
__global__ __launch_bounds__(256) void bvo_kernel(const float* __restrict__ out_w,
                                                  const float* __restrict__ qkv_b,
                                                  const float* __restrict__ out_b,
                                                  float* __restrict__ biasout) {
    const int c = blockIdx.x * 256 + threadIdx.x;   // 512
    const float4* wr = (const float4*)(out_w + (long long)c * 512);
    const float4* bv = (const float4*)(qkv_b + 1024);
    float s = 0.f;
    #pragma unroll 4
    for (int i = 0; i < 128; i++) {
        float4 a = wr[i], b = bv[i];
        s += a.x*b.x + a.y*b.y + a.z*b.z + a.w*b.w;
    }
    biasout[c] = out_b[c] + s;
}

// ---------------- softmax: one wave per row, XCD-affine (batch z -> XCD z&7) ----------------
__global__ __launch_bounds__(256) void softmax_kernel(u16* __restrict__ P) {
    const int lid  = blockIdx.x;            // 4096 blocks
    const int xcd  = lid & 7;
    const int slot = lid >> 3;              // 0..511
    const int j    = slot >> 8;             // 0..1
    const int w    = slot & 255;            // block-in-batch
    const int z    = xcd + 8 * j;
    const int wave = threadIdx.x >> 6, lane = threadIdx.x & 63;
    const long long row = (long long)z * 1024 + w * 4 + wave;
    u16* p = P + row * 1024 + lane * 16;
    u16x8 a = *(u16x8*)p;
    u16x8 b = *(u16x8*)(p + 8);
    float v[16];
    #pragma unroll
    for (int k = 0; k < 8; k++) { v[k] = bf2f(a[k]); v[8+k] = bf2f(b[k]); }
    float mx = v[0];
    #pragma unroll
    for (int k = 1; k < 16; k++) mx = fmaxf(mx, v[k]);
    #pragma unroll
    for (int m = 1; m < 64; m <<= 1) mx = fmaxf(mx, __shfl_xor(mx, m, 64));
    float s = 0.f;
    #pragma unroll
    for (int k = 0; k < 16; k++) { v[k] = __expf(v[k] - mx); s += v[k]; }
    #pragma unroll
    for (int m = 1; m < 64; m <<= 1) s += __shfl_xor(s, m, 64);
    float inv = 1.f / s;
    #pragma unroll
    for (int k = 0; k < 8; k++) { a[k] = f2bf(v[k]*inv); b[k] = f2bf(v[8+k]*inv); }
    *(u16x8*)p = a;
    *(u16x8*)(p + 8) = b;
}

// ---------------- TN GEMM, 128x128 tile, BK=64 ----------------
// MODE 0: fp32 out + bias[m] + residual ([m][n])
// MODE 1: bf16 out, scaled ([m][n])
// MODE 2: bf16 transposed out C0[n][m] + bias[m]
// NX>0: 1D launch of NX*NY*nz blocks, decoded so batch z runs on XCD z&7.
template <int MODE, int NX, int NY>
__global__ __launch_bounds__(256, 3)
void gemm_bt_kernel(const u16* __restrict__ A, const u16* __restrict__ Bt,
                    void* __restrict__ C0,
                    const float* __restrict__ bias, const float* __restrict__ res,
                    float scale, int lda, int ldb, int ldc,
                    long long sA, long long sB, long long sC, long long sR, int K) {
    int bx, by, bz;
    if (NX > 0) {
        const int lid  = blockIdx.x;
        const int xcd  = lid & 7;
        const int slot = lid >> 3;
        const int per  = NX * NY;
        const int j    = slot / per;
        const int w    = slot - j * per;
        bz = xcd + 8 * j;
        bx = w % NX;
        by = w / NX;
    } else {
        bx = blockIdx.x; by = blockIdx.y; bz = blockIdx.z;
    }
    const int t    = threadIdx.x;
    const int lane = t & 63;
    const int wave = t >> 6;
    const int m0   = by * 128;
    const int n0   = bx * 128;
    A  += (long long)bz * sA;
    Bt += (long long)bz * sB;

    __shared__ __align__(16) u16 smem[16384];   // 32 KB: A[2][128][32] | B[2][128][32]
    u16* As = smem;
    u16* Bs = smem + 8192;

    const int wm = wave >> 1, wn = wave & 1;
    const int quad = lane >> 4, lrow = lane & 15;

    floatx4 acc[4][4];
    #pragma unroll
    for (int i = 0; i < 4; i++)
        #pragma unroll
        for (int j = 0; j < 4; j++)
            #pragma unroll
            for (int r = 0; r < 4; r++) acc[i][j][r] = 0.f;

    const int rowA = t >> 2;
    const int kch  = (t & 3) * 8;
    const u16* Ag = A  + (long long)(m0 + rowA) * lda + kch;
    const u16* Bg = Bt + (long long)(n0 + rowA) * ldb + kch;
    u16* Al = &As[t * 8];
    u16* Bl = &Bs[t * 8];
    const long long a64 = (long long)64 * lda;
    const long long b64 = (long long)64 * ldb;

    for (int k0 = 0; k0 < K; k0 += 64) {
        gload_lds16(Ag + k0,            Al);
        gload_lds16(Ag + k0 + a64,      Al + 2048);
        gload_lds16(Ag + k0 + 32,       Al + 4096);
        gload_lds16(Ag + k0 + 32 + a64, Al + 6144);
        gload_lds16(Bg + k0,            Bl);
        gload_lds16(Bg + k0 + b64,      Bl + 2048);
        gload_lds16(Bg + k0 + 32,       Bl + 4096);
        gload_lds16(Bg + k0 + 32 + b64, Bl + 6144);
        __syncthreads();
        #pragma unroll
        for (int kk = 0; kk < 2; kk++) {
            short8 af[4], bfr[4];
            #pragma unroll
            for (int i = 0; i < 4; i++)
                af[i] = *(const short8*)&As[kk*4096 + (wm*64 + i*16 + lrow)*32 + quad*8];
            #pragma unroll
            for (int j = 0; j < 4; j++)
                bfr[j] = *(const short8*)&Bs[kk*4096 + (wn*64 + j*16 + lrow)*32 + quad*8];
            #pragma unroll
            for (int i = 0; i < 4; i++)
                #pragma unroll
                for (int j = 0; j < 4; j++)
                    acc[i][j] = __builtin_amdgcn_mfma_f32_16x16x32_bf16(af[i], bfr[j], acc[i][j], 0, 0, 0);
        }
        __syncthreads();
    }
    // smem free from here

    const int ST = 136;  // u16 row stride (272 B = 17*16)

    if (MODE == 1) {
        #pragma unroll
        for (int p = 0; p < 4; p++) {
            if (p) __syncthreads();
            if (wm == (p >> 1)) {
                #pragma unroll
                for (int ii = 0; ii < 2; ii++) {
                    const int i = (p & 1) * 2 + ii;
                    const int row = ii * 16 + quad * 4;
                    #pragma unroll
                    for (int j = 0; j < 4; j++) {
                        const int cB = wn * 64 + j * 16 + lrow;
                        #pragma unroll
                        for (int r = 0; r < 4; r++)
                            smem[(row + r) * ST + cB] = f2bf(acc[i][j][r] * scale);
                    }
                }
            }
            __syncthreads();
            const int rr = t >> 3, cc = (t & 7) * 16;
            u16x8 a0 = *(u16x8*)&smem[rr * ST + cc];
            u16x8 a1 = *(u16x8*)&smem[rr * ST + cc + 8];
            u16* Cp = (u16*)C0 + (long long)bz * sC + (long long)(m0 + p * 32 + rr) * ldc + n0 + cc;
            *(u16x8*)Cp = a0;
            *(u16x8*)(Cp + 8) = a1;
        }
    } else if (MODE == 2) {
        #pragma unroll
        for (int p = 0; p < 4; p++) {
            if (p) __syncthreads();
            if (wn == (p >> 1)) {
                #pragma unroll
                for (int jj = 0; jj < 2; jj++) {
                    const int j = (p & 1) * 2 + jj;
                    const int row = jj * 16 + lrow;
                    #pragma unroll
                    for (int i = 0; i < 4; i++) {
                        const int mmL = wm * 64 + i * 16 + quad * 4;
                        u16x4 pk;
                        #pragma unroll
                        for (int r = 0; r < 4; r++)
                            pk[r] = f2bf(acc[i][j][r] + bias[m0 + mmL + r]);
                        *(u16x4*)&smem[row * ST + mmL] = pk;
                    }
                }
            }
            __syncthreads();
            const int rr = t >> 3, cc = (t & 7) * 16;
            u16x8 a0 = *(u16x8*)&smem[rr * ST + cc];
            u16x8 a1 = *(u16x8*)&smem[rr * ST + cc + 8];
            u16* Cp = (u16*)C0 + (long long)(n0 + p * 32 + rr) * ldc + m0 + cc;
            *(u16x8*)Cp = a0;
            *(u16x8*)(Cp + 8) = a1;
        }
    } else {
        float* smf = (float*)smem;
        const int SF = 132;
        float* C = (float*)C0 + (long long)bz * sC;
        const float* rz = res + (long long)bz * sR;
        #pragma unroll
        for (int p = 0; p < 8; p++) {
            if (p) __syncthreads();
            if (wm == (p >> 2)) {
                const int i = p & 3;
                #pragma unroll
                for (int j = 0; j < 4; j++) {
                    const int cB = wn * 64 + j * 16 + lrow;
                    #pragma unroll
                    for (int r = 0; r < 4; r++)
                        smf[(quad * 4 + r) * SF + cB] =
                            acc[i][j][r] + bias[m0 + p * 16 + quad * 4 + r];
                }
            }
            __syncthreads();
            const int rr = t >> 4, cc = (t & 15) * 8;
            const long long gro = (long long)(m0 + p * 16 + rr) * ldc + n0 + cc;
            float4 rv0 = *(const float4*)&rz[gro];
            float4 rv1 = *(const float4*)&rz[gro + 4];
            float4 ov0, ov1;
            ov0.x = smf[rr*SF + cc + 0] + rv0.x;
            ov0.y = smf[rr*SF + cc + 1] + rv0.y;
            ov0.z = smf[rr*SF + cc + 2] + rv0.z;
            ov0.w = smf[rr*SF + cc + 3] + rv0.w;
            ov1.x = smf[rr*SF + cc + 4] + rv1.x;
            ov1.y = smf[rr*SF + cc + 5] + rv1.y;
            ov1.z = smf[rr*SF + cc + 6] + rv1.z;
            ov1.w = smf[rr*SF + cc + 7] + rv1.w;
            *(float4*)&C[gro]     = ov0;
            *(float4*)&C[gro + 4] = ov1;
        }
    }
}

extern "C" void kernel_launch(void* const* d_in, const int* in_sizes, int n_in,
                              void* d_out, int out_size, void* d_ws, size_t ws_size,
                              hipStream_t stream) {
    (void)in_sizes; (void)n_in; (void)out_size; (void)ws_size;
    const float* x     = (const float*)d_in[0];
    const float* gn_w  = (const float*)d_in[1];
    const float* gn_b  = (const float*)d_in[2];
    const float* qkv_w = (const float*)d_in[3];
    const float* qkv_b = (const float*)d_in[4];
    const float* out_w = (const float*)d_in[5];
    const float* out_b = (const float*)d_in[6];
    float* out = (float*)d_out;

    char* ws = (char*)d_ws;
    u16*  h_t   = (u16*)ws;  ws += (size_t)16*1024*512*2;    // 16 MB h[b][n][c]
    u16*  qkv_t = (u16*)ws;  ws += (size_t)16*1024*1024*2;   // 32 MB qk[b*n][1024]
    u16*  vprm  = (u16*)ws;  ws += (size_t)512*16384*2;      // 16 MB V' = Wvo ⊗ h : [c_out][b*1024+n]
    u16*  S     = (u16*)ws;  ws += (size_t)16*1024*1024*2;   // 32 MB S/P[b][n][m]
    u16*  wqk   = (u16*)ws;  ws += (size_t)1024*512*2;       // q,k weights bf16
    u16*  wo    = (u16*)ws;  ws += (size_t)512*512*2;        // out weights bf16
    u16*  wvT   = (u16*)ws;  ws += (size_t)512*512*2;        // v-weights transposed [ci][cv]
    u16*  wvo   = (u16*)ws;  ws += (size_t)512*512*2;        // Wvo = Wo@Wv bf16 [c][ci]
    float* biasout = (float*)ws; ws += (size_t)512*4;        // out_b + Wo@bv

    wprep_kernel<<<1024, 256, 0, stream>>>(qkv_w, wqk, out_w, wo, wvT);
    bvo_kernel<<<2, 256, 0, stream>>>(out_w, qkv_b, out_b, biasout);
    gn_fused_kernel<<<512, 256, 0, stream>>>(x, gn_w, gn_b, h_t);

    // Wvo = Wo @ Wv : M=512(c), N=512(ci), K=512(cv); A=wo, Bt=wvT
    gemm_bt_kernel<1, 0, 0><<<dim3(4, 4, 1), 256, 0, stream>>>(
        wo, wvT, wvo, nullptr, nullptr, 1.0f,
        512, 512, 512, 0, 0, 0, 0, 512);

    // QK: M=1024, Nn=16384, K=512 ; transposed -> qkv_t[bn][1024] + bias
    gemm_bt_kernel<2, 0, 0><<<dim3(128, 8, 1), 256, 0, stream>>>(
        wqk, h_t, qkv_t, qkv_b, nullptr, 1.0f,
        512, 512, 1024, 0, 0, 0, 0, 512);

    // V' = Wvo ⊗ h : M=512(c_out), Nn=16384(bn), K=512(ci)
    gemm_bt_kernel<1, 0, 0><<<dim3(128, 4, 1), 256, 0, stream>>>(
        wvo, h_t, vprm, nullptr, nullptr, 1.0f,
        512, 512, 16384, 0, 0, 0, 0, 512);

    // S = q k^T * scale : per batch M=Nn=1024, K=512 ; XCD-affine (z&7)
    gemm_bt_kernel<1, 8, 8><<<1024, 256, 0, stream>>>(
        qkv_t, qkv_t + 512, S, nullptr, nullptr, 0.044194173824159216f,
        1024, 1024, 1024,
        (long long)1024*1024, (long long)1024*1024, (long long)1024*1024, 0, 512);

    softmax_kernel<<<4096, 256, 0, stream>>>(S);

    // out = vprm ⊗ P + biasout + x : M=512(c_out), Nn=1024(n), K=1024 ; XCD-affine
    gemm_bt_kernel<0, 8, 4><<<512, 256, 0, stream>>>(
        vprm, S, out, biasout, x, 1.0f,
        16384, 1024, 1024,
        1024, (long long)1024*1024, (long long)512*1024, (long long)512*1024, 1024);
}

// Round 8
// 213.558 us; speedup vs baseline: 1.0832x; 1.0832x over previous
//
#include <hip/hip_runtime.h>

typedef unsigned short u16;
typedef short short8 __attribute__((ext_vector_type(8)));
typedef float floatx4 __attribute__((ext_vector_type(4)));
typedef u16 u16x4 __attribute__((ext_vector_type(4)));
typedef u16 u16x8 __attribute__((ext_vector_type(8)));

#define DEVI __device__ __forceinline__

DEVI u16 f2bf(float x) {
    union { float f; unsigned u; } c; c.f = x;
    unsigned u = c.u;
    u += 0x7fffu + ((u >> 16) & 1u);   // RNE
    return (u16)(u >> 16);
}
DEVI u16 f2bf_fast(float x) {   // round-half-up, 2 ops — staging only
    union { float f; unsigned u; } c; c.f = x;
    return (u16)((c.u + 0x8000u) >> 16);
}
DEVI float bf2f(u16 h) {
    union { unsigned u; float f; } c; c.u = ((unsigned)h) << 16;
    return c.f;
}

DEVI void gload_lds16(const void* g, void* l) {
    auto gp = (const __attribute__((address_space(1))) unsigned*)(unsigned long long)g;
    auto lp = (__attribute__((address_space(3))) unsigned*)(unsigned)(unsigned long long)l;
    __builtin_amdgcn_global_load_lds(gp, lp, 16, 0, 0);
}

// ---------------- fused GroupNorm: single global read, stats + apply in regs ----------------
__global__ __launch_bounds__(256) void gn_fused_kernel(const float* __restrict__ x,
                                                       const float* __restrict__ w,
                                                       const float* __restrict__ bb,
                                                       u16* __restrict__ h) {
    const int bg = blockIdx.x;           // b*32+g
    const int b = bg >> 5, g = bg & 31;
    const float* xg = x + (long long)bg * 16384;
    const int n0 = threadIdx.x * 4;

    float4 xv[16];
    float s = 0.f, s2 = 0.f;
    #pragma unroll
    for (int cc = 0; cc < 16; cc++) {
        xv[cc] = *(const float4*)&xg[cc * 1024 + n0];
        s  += xv[cc].x + xv[cc].y + xv[cc].z + xv[cc].w;
        s2 += xv[cc].x*xv[cc].x + xv[cc].y*xv[cc].y + xv[cc].z*xv[cc].z + xv[cc].w*xv[cc].w;
    }
    #pragma unroll
    for (int m = 1; m < 64; m <<= 1) { s += __shfl_xor(s, m, 64); s2 += __shfl_xor(s2, m, 64); }
    __shared__ float rs[4], rq[4];
    if ((threadIdx.x & 63) == 0) { rs[threadIdx.x >> 6] = s; rq[threadIdx.x >> 6] = s2; }
    __syncthreads();
    float mean = (rs[0] + rs[1] + rs[2] + rs[3]) * (1.f / 16384.f);
    float var  = (rq[0] + rq[1] + rq[2] + rq[3]) * (1.f / 16384.f) - mean * mean;
    float rstd = rsqrtf(var + 1e-5f);

    u16x8 o[4][2];
    #pragma unroll
    for (int cc = 0; cc < 16; cc++) {
        int c = g * 16 + cc;
        float sc = w[c] * rstd;
        float sh = bb[c] - mean * sc;
        o[0][cc >> 3][cc & 7] = f2bf(xv[cc].x * sc + sh);
        o[1][cc >> 3][cc & 7] = f2bf(xv[cc].y * sc + sh);
        o[2][cc >> 3][cc & 7] = f2bf(xv[cc].z * sc + sh);
        o[3][cc >> 3][cc & 7] = f2bf(xv[cc].w * sc + sh);
    }
    u16* hb = h + ((long long)b * 1024 + n0) * 512 + g * 16;
    #pragma unroll
    for (int k = 0; k < 4; k++) {
        *(u16x8*)&hb[(long long)k * 512]     = o[k][0];
        *(u16x8*)&hb[(long long)k * 512 + 8] = o[k][1];
    }
}

// ---------------- both weight conversions in one launch ----------------
__global__ __launch_bounds__(256) void wconv_kernel(const float* __restrict__ w1, u16* __restrict__ o1,
                                                    const float* __restrict__ w2, u16* __restrict__ o2) {
    int i = blockIdx.x * 256 + threadIdx.x;   // of 262144 float4 slots
    const float* src; u16* dst; int j;
    if (i < 196608) { src = w1; dst = o1; j = i; }
    else            { src = w2; dst = o2; j = i - 196608; }
    float4 v = *(const float4*)&src[j * 4];
    u16x4 p; p[0] = f2bf(v.x); p[1] = f2bf(v.y); p[2] = f2bf(v.z); p[3] = f2bf(v.w);
    *(u16x4*)&dst[j * 4] = p;
}

// ---------------- invl[z][n] = 1 / sum_kb psum[z][kb][n] ----------------
__global__ __launch_bounds__(256) void lreduce_kernel(const float* __restrict__ ps,
                                                      float* __restrict__ invl) {
    int i = blockIdx.x * 256 + threadIdx.x;   // 16384 = z*1024+n
    int z = i >> 10, n = i & 1023;
    float l = 0.f;
    #pragma unroll
    for (int kb = 0; kb < 8; kb++) l += ps[((z * 8 + kb) << 10) + n];
    invl[i] = 1.f / l;
}

// ---------------- TN GEMM, 128x128 tile, BK=64 ----------------
// MODE 1: bf16 out, scaled ([m][n]); STATS: also emit per-row partial sum(exp) per key-block
// MODE 2: bf16 transposed out C0[n][m] + bias[m]
// MODE 3: out-fused: Bt staged as exp(S) via VGPRs; fp32 out = acc*invl[n] + bias[m] + res
// NX>0: 1D launch, decoded so batch z runs on XCD z&7.
template <int MODE, int NX, int NY, bool STATS>
__global__ __launch_bounds__(256, 3)
void gemm_bt_kernel(const u16* __restrict__ A, const u16* __restrict__ Bt,
                    void* __restrict__ C0,
                    const float* __restrict__ bias, const float* __restrict__ res,
                    float* __restrict__ aux,
                    float scale, int lda, int ldb, int ldc,
                    long long sA, long long sB, long long sC, long long sR, int K) {
    int bx, by, bz;
    if (NX > 0) {
        const int lid  = blockIdx.x;
        const int xcd  = lid & 7;
        const int slot = lid >> 3;
        const int per  = NX * NY;
        const int j    = slot / per;
        const int w    = slot - j * per;
        bz = xcd + 8 * j;
        bx = w % NX;
        by = w / NX;
    } else {
        bx = blockIdx.x; by = blockIdx.y; bz = blockIdx.z;
    }
    const int t    = threadIdx.x;
    const int lane = t & 63;
    const int wave = t >> 6;
    const int m0   = by * 128;
    const int n0   = bx * 128;
    A  += (long long)bz * sA;
    Bt += (long long)bz * sB;

    __shared__ __align__(16) u16 smem[16384];   // 32 KB: A[2][128][32] | B[2][128][32]
    u16* As = smem;
    u16* Bs = smem + 8192;

    const int wm = wave >> 1, wn = wave & 1;
    const int quad = lane >> 4, lrow = lane & 15;

    floatx4 acc[4][4];
    #pragma unroll
    for (int i = 0; i < 4; i++)
        #pragma unroll
        for (int j = 0; j < 4; j++)
            #pragma unroll
            for (int r = 0; r < 4; r++) acc[i][j][r] = 0.f;

    const int rowA = t >> 2;
    const int kch  = (t & 3) * 8;
    const u16* Ag = A  + (long long)(m0 + rowA) * lda + kch;
    const u16* Bg = Bt + (long long)(n0 + rowA) * ldb + kch;
    u16* Al = &As[t * 8];
    u16* Bl = &Bs[t * 8];
    const long long a64 = (long long)64 * lda;
    const long long b64 = (long long)64 * ldb;
    const u16* Bg3 = Bt + (long long)n0 * ldb;   // MODE3 row base

    for (int k0 = 0; k0 < K; k0 += 64) {
        gload_lds16(Ag + k0,            Al);
        gload_lds16(Ag + k0 + a64,      Al + 2048);
        gload_lds16(Ag + k0 + 32,       Al + 4096);
        gload_lds16(Ag + k0 + 32 + a64, Al + 6144);
        if (MODE != 3) {
            gload_lds16(Bg + k0,            Bl);
            gload_lds16(Bg + k0 + b64,      Bl + 2048);
            gload_lds16(Bg + k0 + 32,       Bl + 4096);
            gload_lds16(Bg + k0 + 32 + b64, Bl + 6144);
        } else {
            // stage exp(S) through VGPRs, same LDS layout as the DMA path
            #pragma unroll
            for (int q = 0; q < 4; q++) {
                const int row = ((q & 1) ? 64 : 0) + (t >> 2);
                const int kc  = (q >> 1) * 32 + (t & 3) * 8;
                u16x8 sv = *(const u16x8*)&Bg3[(long long)row * ldb + k0 + kc];
                u16x8 ev;
                #pragma unroll
                for (int e = 0; e < 8; e++)
                    ev[e] = f2bf_fast(__expf(bf2f(sv[e])));
                *(u16x8*)&Bs[q * 2048 + t * 8] = ev;
            }
        }
        __syncthreads();
        #pragma unroll
        for (int kk = 0; kk < 2; kk++) {
            short8 af[4], bfr[4];
            #pragma unroll
            for (int i = 0; i < 4; i++)
                af[i] = *(const short8*)&As[kk*4096 + (wm*64 + i*16 + lrow)*32 + quad*8];
            #pragma unroll
            for (int j = 0; j < 4; j++)
                bfr[j] = *(const short8*)&Bs[kk*4096 + (wn*64 + j*16 + lrow)*32 + quad*8];
            #pragma unroll
            for (int i = 0; i < 4; i++)
                #pragma unroll
                for (int j = 0; j < 4; j++)
                    acc[i][j] = __builtin_amdgcn_mfma_f32_16x16x32_bf16(af[i], bfr[j], acc[i][j], 0, 0, 0);
        }
        __syncthreads();
    }
    // smem free from here

    const int ST = 136;  // u16 row stride (272 B = 17*16)

    if (MODE == 1) {
        #pragma unroll
        for (int p = 0; p < 4; p++) {
            if (p) __syncthreads();
            if (wm == (p >> 1)) {
                #pragma unroll
                for (int ii = 0; ii < 2; ii++) {
                    const int i = (p & 1) * 2 + ii;
                    const int row = ii * 16 + quad * 4;
                    #pragma unroll
                    for (int j = 0; j < 4; j++) {
                        const int cB = wn * 64 + j * 16 + lrow;
                        #pragma unroll
                        for (int r = 0; r < 4; r++)
                            smem[(row + r) * ST + cB] = f2bf(acc[i][j][r] * scale);
                    }
                }
            }
            __syncthreads();
            const int rr = t >> 3, cc = (t & 7) * 16;
            u16x8 a0 = *(u16x8*)&smem[rr * ST + cc];
            u16x8 a1 = *(u16x8*)&smem[rr * ST + cc + 8];
            u16* Cp = (u16*)C0 + (long long)bz * sC + (long long)(m0 + p * 32 + rr) * ldc + n0 + cc;
            *(u16x8*)Cp = a0;
            *(u16x8*)(Cp + 8) = a1;
            if (STATS) {
                // partial sum of exp over this block's 128 key-cols, per query row
                float ls = 0.f;
                #pragma unroll
                for (int e = 0; e < 8; e++)
                    ls += __expf(bf2f(a0[e])) + __expf(bf2f(a1[e]));
                #pragma unroll
                for (int m2 = 1; m2 < 8; m2 <<= 1) ls += __shfl_xor(ls, m2, 8);
                if ((t & 7) == 0)
                    aux[((long long)(bz * 8 + bx)) * 1024 + m0 + p * 32 + rr] = ls;
            }
        }
    } else if (MODE == 2) {
        #pragma unroll
        for (int p = 0; p < 4; p++) {
            if (p) __syncthreads();
            if (wn == (p >> 1)) {
                #pragma unroll
                for (int jj = 0; jj < 2; jj++) {
                    const int j = (p & 1) * 2 + jj;
                    const int row = jj * 16 + lrow;
                    #pragma unroll
                    for (int i = 0; i < 4; i++) {
                        const int mmL = wm * 64 + i * 16 + quad * 4;
                        u16x4 pk;
                        #pragma unroll
                        for (int r = 0; r < 4; r++)
                            pk[r] = f2bf(acc[i][j][r] + bias[m0 + mmL + r]);
                        *(u16x4*)&smem[row * ST + mmL] = pk;
                    }
                }
            }
            __syncthreads();
            const int rr = t >> 3, cc = (t & 7) * 16;
            u16x8 a0 = *(u16x8*)&smem[rr * ST + cc];
            u16x8 a1 = *(u16x8*)&smem[rr * ST + cc + 8];
            u16* Cp = (u16*)C0 + (long long)(n0 + p * 32 + rr) * ldc + m0 + cc;
            *(u16x8*)Cp = a0;
            *(u16x8*)(Cp + 8) = a1;
        }
    } else {
        // MODE 3: fp32 out = acc*invl[col] + bias[row] + res
        float* smf = (float*)smem;
        const int SF = 132;
        float* C = (float*)C0 + (long long)bz * sC;
        const float* rz = res + (long long)bz * sR;
        const float* il = aux + (long long)bz * 1024;
        #pragma unroll
        for (int p = 0; p < 8; p++) {
            if (p) __syncthreads();
            if (wm == (p >> 2)) {
                const int i = p & 3;
                #pragma unroll
                for (int j = 0; j < 4; j++) {
                    const int cB = wn * 64 + j * 16 + lrow;
                    #pragma unroll
                    for (int r = 0; r < 4; r++)
                        smf[(quad * 4 + r) * SF + cB] = acc[i][j][r];
                }
            }
            __syncthreads();
            const int rr = t >> 4, cc = (t & 15) * 8;
            const float bsv = bias[m0 + p * 16 + rr];
            float4 il0 = *(const float4*)&il[n0 + cc];
            float4 il1 = *(const float4*)&il[n0 + cc + 4];
            const long long gro = (long long)(m0 + p * 16 + rr) * ldc + n0 + cc;
            float4 rv0 = *(const float4*)&rz[gro];
            float4 rv1 = *(const float4*)&rz[gro + 4];
            float4 ov0, ov1;
            ov0.x = smf[rr*SF + cc + 0] * il0.x + bsv + rv0.x;
            ov0.y = smf[rr*SF + cc + 1] * il0.y + bsv + rv0.y;
            ov0.z = smf[rr*SF + cc + 2] * il0.z + bsv + rv0.z;
            ov0.w = smf[rr*SF + cc + 3] * il0.w + bsv + rv0.w;
            ov1.x = smf[rr*SF + cc + 4] * il1.x + bsv + rv1.x;
            ov1.y = smf[rr*SF + cc + 5] * il1.y + bsv + rv1.y;
            ov1.z = smf[rr*SF + cc + 6] * il1.z + bsv + rv1.z;
            ov1.w = smf[rr*SF + cc + 7] * il1.w + bsv + rv1.w;
            *(float4*)&C[gro]     = ov0;
            *(float4*)&C[gro + 4] = ov1;
        }
    }
}

extern "C" void kernel_launch(void* const* d_in, const int* in_sizes, int n_in,
                              void* d_out, int out_size, void* d_ws, size_t ws_size,
                              hipStream_t stream) {
    (void)in_sizes; (void)n_in; (void)out_size; (void)ws_size;
    const float* x     = (const float*)d_in[0];
    const float* gn_w  = (const float*)d_in[1];
    const float* gn_b  = (const float*)d_in[2];
    const float* qkv_w = (const float*)d_in[3];
    const float* qkv_b = (const float*)d_in[4];
    const float* out_w = (const float*)d_in[5];
    const float* out_b = (const float*)d_in[6];
    float* out = (float*)d_out;

    char* ws = (char*)d_ws;
    u16*  h_t   = (u16*)ws;  ws += (size_t)16*1024*512*2;    // 16 MB h[b][n][c]
    u16*  qkv_t = (u16*)ws;  ws += (size_t)16*1024*1536*2;   // 48 MB qkv[b*n][1536]
    u16*  vprm  = (u16*)ws;  ws += (size_t)512*16384*2;      // 16 MB V' = Wo V^T : [c_out][b*1024+n]
    u16*  S     = (u16*)ws;  ws += (size_t)16*1024*1024*2;   // 32 MB S[b][n][m] (bf16, scaled)
    u16*  wq    = (u16*)ws;  ws += (size_t)1536*512*2;
    u16*  wo    = (u16*)ws;  ws += (size_t)512*512*2;
    float* psum = (float*)ws; ws += (size_t)16*8*1024*4;     // partial sum(exp) per key-block
    float* invl = (float*)ws; ws += (size_t)16*1024*4;       // 1/rowsum

    wconv_kernel<<<1024, 256, 0, stream>>>(qkv_w, wq, out_w, wo);
    gn_fused_kernel<<<512, 256, 0, stream>>>(x, gn_w, gn_b, h_t);

    // QKV: M=1536, Nn=16384, K=512 ; all transposed -> qkv_t[bn][1536] + bias
    gemm_bt_kernel<2, 0, 0, false><<<dim3(128, 12, 1), 256, 0, stream>>>(
        wq, h_t, qkv_t, qkv_b, nullptr, nullptr, 1.0f,
        512, 512, 1536, 0, 0, 0, 0, 512);

    // V' = Wo @ V^T : M=512(c_out), Nn=16384(bn), K=512(c_in)
    gemm_bt_kernel<1, 0, 0, false><<<dim3(128, 4, 1), 256, 0, stream>>>(
        wo, qkv_t + 1024, vprm, nullptr, nullptr, nullptr, 1.0f,
        512, 1536, 16384, 0, 0, 0, 0, 512);

    // S = q k^T * scale : per batch M=Nn=1024, K=512 ; XCD-affine + partial expsum stats
    gemm_bt_kernel<1, 8, 8, true><<<1024, 256, 0, stream>>>(
        qkv_t, qkv_t + 512, S, nullptr, nullptr, psum, 0.044194173824159216f,
        1536, 1536, 1024,
        (long long)1024*1536, (long long)1024*1536, (long long)1024*1024, 0, 512);

    lreduce_kernel<<<64, 256, 0, stream>>>(psum, invl);

    // out = vprm ⊗ exp(S) * invl + out_b + x : M=512, Nn=1024(n), K=1024(m) ; XCD-affine
    gemm_bt_kernel<3, 8, 4, false><<<512, 256, 0, stream>>>(
        vprm, S, out, out_b, x, invl, 1.0f,
        16384, 1024, 1024,
        1024, (long long)1024*1024, (long long)512*1024, (long long)512*1024, 1024);
}